// Round 11
// baseline (412.624 us; speedup 1.0000x reference)
//
#include <hip/hip_runtime.h>
#include <hip/hip_bf16.h>
#include <math.h>

using bf16 = __hip_bfloat16;
typedef __bf16 bf16x8 __attribute__((ext_vector_type(8)));
typedef short  short4v __attribute__((ext_vector_type(4)));
typedef float  f32x4  __attribute__((ext_vector_type(4)));

static constexpr int Lq = 2048, Nb = 2, E = 1024, Hh = 16, Dd = 64, Ff = 4096;
static constexpr int MT = Lq * Nb;          // 4096 tokens
static constexpr int QKLD = 2 * E;          // 2048: q|k row stride per token
static constexpr int LDL = 2 * QKLD;        // 4096: stride per seq-step l

__device__ __forceinline__ void async_lds16(const void* g, void* l) {
  __builtin_amdgcn_global_load_lds(
      (const __attribute__((address_space(1))) void*)g,
      (__attribute__((address_space(3))) void*)l, 16, 0, 0);
}
__device__ __forceinline__ bf16x8 ld8(const bf16* p) { return *(const bf16x8*)p; }
__device__ __forceinline__ short bfbits(float x) {
  bf16 t = __float2bfloat16(x);
  return *(short*)&t;
}
// fast gelu (tanh form, reduced): gelu(v) = v * t/(t+1),
// t = exp2(2.302208*(v + 0.044715 v^3)); max abs err ~1e-3
__device__ __forceinline__ float gelu_fast(float v) {
  const float y = fminf(2.302208f * (v + 0.044715f * v * v * v), 80.f);
  const float t = exp2f(y);
  return v * t / (t + 1.0f);
}

// ---------------------------------------------------------------------------
// Fused f32 -> bf16 cast of all 6 weight matrices in ONE dispatch.
// ---------------------------------------------------------------------------
__global__ __launch_bounds__(256) void cvt_all_kernel(
    const float* __restrict__ wq, const float* __restrict__ wk,
    const float* __restrict__ wv, const float* __restrict__ wout,
    const float* __restrict__ fc1w, const float* __restrict__ fc2w,
    bf16* __restrict__ wqkvb, bf16* __restrict__ woutb,
    bf16* __restrict__ f1wb, bf16* __restrict__ f2wb) {
  const int i = blockIdx.x * 256 + threadIdx.x;
  const float* src;
  bf16* dst;
  size_t off;
  if (i < 786432) {            // qkv: three E*E blocks concat in wqkvb
    const int r = i >> 18;     // 0,1,2
    off = (size_t)(i & 262143);
    src = (r == 0) ? wq : (r == 1) ? wk : wv;
    dst = wqkvb + (size_t)r * (E * E);
  } else if (i < 1048576) {
    off = (size_t)(i - 786432); src = wout; dst = woutb;
  } else if (i < 2097152) {
    off = (size_t)(i - 1048576); src = fc1w; dst = f1wb;
  } else {
    off = (size_t)(i - 2097152); src = fc2w; dst = f2wb;
  }
  float4 v = ((const float4*)src)[off];
  bf16 o4[4] = {__float2bfloat16(v.x), __float2bfloat16(v.y),
                __float2bfloat16(v.z), __float2bfloat16(v.w)};
  *(uint2*)(dst + 4 * off) = *(uint2*)o4;
}

// ---------------------------------------------------------------------------
// GEMM (R9-proven BK=32 structure): C[m][n] = sum_k A[m][k]*W[n][k].
// 128x128 tile, BK=32, 4 waves 2x2, each wave 64x64 via 4x4 of 16x16x32 MFMA.
// EPI 2: gelu_fast(acc+bias) -> bf16
// EPI 3: acc -> bf16 partial at z*MT*E (split-K, no bias)
// EPI 4: QKV: ncol<2048 -> outb[token][2048]; ncol>=2048 -> V^T scatter
// ---------------------------------------------------------------------------
template <int EPI>
__global__ __launch_bounds__(256) void gemm_bt(
    const bf16* __restrict__ A, const bf16* __restrict__ W,
    const float* __restrict__ b1, const float* __restrict__ b2,
    const float* __restrict__ b3, int Klen, int Kstride, int Nld,
    float qscale, int scut, bf16* __restrict__ outb,
    bf16* __restrict__ outv) {
  __shared__ __align__(16) bf16 As[128 * 32];
  __shared__ __align__(16) bf16 Bs[128 * 32];
  const int tid = threadIdx.x;
  const int w = tid >> 6, lane = tid & 63;
  const int quad = lane >> 4, l16 = lane & 15;
  const int wm = (w >> 1) * 64, wn = (w & 1) * 64;
  const int m0 = blockIdx.y * 128, n0 = blockIdx.x * 128;
  const int koff = blockIdx.z * Klen;

  f32x4 acc[4][4];
#pragma unroll
  for (int i = 0; i < 4; i++)
#pragma unroll
    for (int j = 0; j < 4; j++)
#pragma unroll
      for (int r = 0; r < 4; r++) acc[i][j][r] = 0.f;

  const int c0 = w * 64 + lane;
  const int c1 = c0 + 256;
  const size_t arow0 = (size_t)(m0 + (c0 >> 2)), arow1 = (size_t)(m0 + (c1 >> 2));
  const size_t brow0 = (size_t)(n0 + (c0 >> 2)), brow1 = (size_t)(n0 + (c1 >> 2));
  const int col0 = (c0 & 3) * 8, col1 = (c1 & 3) * 8;
  bf16* ldsA0 = &As[(w * 64) * 8];
  bf16* ldsA1 = &As[(256 + w * 64) * 8];
  bf16* ldsB0 = &Bs[(w * 64) * 8];
  bf16* ldsB1 = &Bs[(256 + w * 64) * 8];

  const int nk = Klen >> 5;
  for (int kt = 0; kt < nk; ++kt) {
    const int k0 = koff + kt * 32;
    async_lds16(A + arow0 * Kstride + k0 + col0, ldsA0);
    async_lds16(A + arow1 * Kstride + k0 + col1, ldsA1);
    async_lds16(W + brow0 * Kstride + k0 + col0, ldsB0);
    async_lds16(W + brow1 * Kstride + k0 + col1, ldsB1);
    __syncthreads();
    bf16x8 a[4], b[4];
#pragma unroll
    for (int i = 0; i < 4; i++) {
      a[i] = ld8(&As[(wm + i * 16 + l16) * 32 + quad * 8]);
      b[i] = ld8(&Bs[(wn + i * 16 + l16) * 32 + quad * 8]);
    }
#pragma unroll
    for (int i = 0; i < 4; i++)
#pragma unroll
      for (int j = 0; j < 4; j++)
        acc[i][j] = __builtin_amdgcn_mfma_f32_16x16x32_bf16(a[i], b[j], acc[i][j], 0, 0, 0);
    __syncthreads();
  }

  const size_t zoff = (EPI == 3) ? (size_t)blockIdx.z * ((size_t)MT * E) : 0;
#pragma unroll
  for (int i = 0; i < 4; i++) {
    const int mrow = m0 + wm + i * 16 + quad * 4;
#pragma unroll
    for (int j = 0; j < 4; j++) {
      const int ncol = n0 + wn + j * 16 + l16;
      float bv = 0.f;
      if constexpr (EPI != 3) {
        if (b3 != nullptr) {
          bv = (ncol < 1024) ? b1[ncol]
               : (ncol < 2048) ? b2[ncol - 1024] : b3[ncol - 2048];
        } else {
          bv = b1[ncol];
        }
      }
      const float sc = (ncol < scut) ? qscale : 1.0f;
#pragma unroll
      for (int r = 0; r < 4; r++) {
        float v = (acc[i][j][r] + bv) * sc;
        if constexpr (EPI == 2) {
          outb[(size_t)(mrow + r) * Nld + ncol] = __float2bfloat16(gelu_fast(v));
        } else if constexpr (EPI == 3) {
          outb[zoff + (size_t)(mrow + r) * Nld + ncol] = __float2bfloat16(v);
        } else {  // EPI 4: QKV
          if (ncol < 2048) {
            outb[(size_t)(mrow + r) * 2048 + ncol] = __float2bfloat16(v);
          } else {
            const int h = (ncol - 2048) >> 6, d = ncol & 63;
            const int tok = mrow + r, n = tok & 1, l = tok >> 1;
            outv[(size_t)((n * 16 + h) * 64 + d) * Lq + l] = __float2bfloat16(v);
          }
        }
      }
    }
  }
}

// ---------------------------------------------------------------------------
// Split-K reduce: out[i] = P0[i] + P1[i] + bias[col] + res[i]   (f32 out)
// ---------------------------------------------------------------------------
__global__ __launch_bounds__(256) void reduce2_kernel(
    const bf16* __restrict__ P, const float* __restrict__ bias,
    const float* __restrict__ res, float* __restrict__ out) {
  const int i = blockIdx.x * 256 + threadIdx.x;  // float4 index
  const size_t e0 = (size_t)i * 4;
  const int col = (int)(e0 & (E - 1));
  uint2 u0 = *(const uint2*)(P + e0);
  uint2 u1 = *(const uint2*)(P + (size_t)MT * E + e0);
  const bf16* p0 = (const bf16*)&u0;
  const bf16* p1 = (const bf16*)&u1;
  float4 b = *(const float4*)(bias + col);
  float4 r = *(const float4*)(res + e0);
  float4 o;
  o.x = (float)p0[0] + (float)p1[0] + b.x + r.x;
  o.y = (float)p0[1] + (float)p1[1] + b.y + r.y;
  o.z = (float)p0[2] + (float)p1[2] + b.z + r.z;
  o.w = (float)p0[3] + (float)p1[3] + b.w + r.w;
  *(float4*)(out + e0) = o;
}

// ---------------------------------------------------------------------------
// Fused out-proj reduce + LayerNorm2. One block per token.
// ---------------------------------------------------------------------------
__global__ __launch_bounds__(256) void redln_kernel(
    const bf16* __restrict__ P, const float* __restrict__ bias,
    const float* __restrict__ res, const float* __restrict__ wgt,
    const float* __restrict__ bia, float* __restrict__ x1,
    bf16* __restrict__ h2) {
  const int t = blockIdx.x, tid = threadIdx.x;
  const size_t base = (size_t)t * E;
  const int e0 = tid * 4;
  uint2 u0 = *(const uint2*)(P + base + e0);
  uint2 u1 = *(const uint2*)(P + (size_t)MT * E + base + e0);
  const bf16* p0 = (const bf16*)&u0;
  const bf16* p1 = (const bf16*)&u1;
  float4 b = *(const float4*)(bias + e0);
  float4 r = *(const float4*)(res + base + e0);
  float v4[4];
  v4[0] = (float)p0[0] + (float)p1[0] + b.x + r.x;
  v4[1] = (float)p0[1] + (float)p1[1] + b.y + r.y;
  v4[2] = (float)p0[2] + (float)p1[2] + b.z + r.z;
  v4[3] = (float)p0[3] + (float)p1[3] + b.w + r.w;
  *(float4*)(x1 + base + e0) = *(float4*)v4;

  float s = 0.f, ss = 0.f;
#pragma unroll
  for (int i = 0; i < 4; i++) { s += v4[i]; ss += v4[i] * v4[i]; }
  for (int off = 32; off > 0; off >>= 1) {
    s += __shfl_down(s, off, 64);
    ss += __shfl_down(ss, off, 64);
  }
  __shared__ float rs[4], rss[4], mv[2];
  const int w = tid >> 6;
  if ((tid & 63) == 0) { rs[w] = s; rss[w] = ss; }
  __syncthreads();
  if (tid == 0) {
    float S = rs[0] + rs[1] + rs[2] + rs[3];
    float SS = rss[0] + rss[1] + rss[2] + rss[3];
    float mean = S * (1.f / E);
    float var = SS * (1.f / E) - mean * mean;
    mv[0] = mean; mv[1] = rsqrtf(var + 1e-5f);
  }
  __syncthreads();
  const float mean = mv[0], rstd = mv[1];
  float4 wg = *(const float4*)(wgt + e0);
  float4 bb = *(const float4*)(bia + e0);
  bf16 o4[4];
  o4[0] = __float2bfloat16((v4[0] - mean) * rstd * wg.x + bb.x);
  o4[1] = __float2bfloat16((v4[1] - mean) * rstd * wg.y + bb.y);
  o4[2] = __float2bfloat16((v4[2] - mean) * rstd * wg.z + bb.z);
  o4[3] = __float2bfloat16((v4[3] - mean) * rstd * wg.w + bb.w);
  *(uint2*)(h2 + base + e0) = *(uint2*)o4;
}

// ---------------------------------------------------------------------------
// LayerNorm over E=1024 per token (f32 in, bf16 out). One block per token.
// ---------------------------------------------------------------------------
__global__ __launch_bounds__(256) void ln_kernel(
    const float* __restrict__ x, const float* __restrict__ wgt,
    const float* __restrict__ bia, bf16* __restrict__ out) {
  const int t = blockIdx.x, tid = threadIdx.x;
  const size_t base = (size_t)t * E;
  float v4[4], s = 0.f, ss = 0.f;
#pragma unroll
  for (int i = 0; i < 4; i++) {
    float v = x[base + i * 256 + tid];
    v4[i] = v; s += v; ss += v * v;
  }
  for (int off = 32; off > 0; off >>= 1) {
    s += __shfl_down(s, off, 64);
    ss += __shfl_down(ss, off, 64);
  }
  __shared__ float rs[4], rss[4], mv[2];
  const int w = tid >> 6;
  if ((tid & 63) == 0) { rs[w] = s; rss[w] = ss; }
  __syncthreads();
  if (tid == 0) {
    float S = rs[0] + rs[1] + rs[2] + rs[3];
    float SS = rss[0] + rss[1] + rss[2] + rss[3];
    float mean = S * (1.f / E);
    float var = SS * (1.f / E) - mean * mean;
    mv[0] = mean; mv[1] = rsqrtf(var + 1e-5f);
  }
  __syncthreads();
  const float mean = mv[0], rstd = mv[1];
#pragma unroll
  for (int i = 0; i < 4; i++) {
    const int e = i * 256 + tid;
    float r = (v4[i] - mean) * rstd * wgt[e] + bia[e];
    out[base + e] = __float2bfloat16(r);
  }
}

// ---------------------------------------------------------------------------
// Flash attention v7 (R9-proven): paired q-tiles, wave-uniform
// global_load_lds staging, S^T register softmax (exp2 domain).
// ---------------------------------------------------------------------------
__global__ __launch_bounds__(256) void attn_kernel(
    const bf16* __restrict__ QK, const bf16* __restrict__ VT,
    bf16* __restrict__ O) {
  __shared__ __align__(16) bf16 KB[512 * 8];  // 8 KB
  __shared__ __align__(16) bf16 VB[512 * 8];  // 8 KB
  const int tid = threadIdx.x;
  const int w = tid >> 6, lane = tid & 63, quad = lane >> 4, l16 = lane & 15;
  const int pid = blockIdx.x;   // 0..15
  const int hh = blockIdx.y;    // 0..31
  const int n = hh >> 4, h = hh & 15;

  const bf16* Qp = QK + n * QKLD + h * Dd;
  const bf16* Kp = Qp + E;
  const bf16* Vp = VT + (size_t)hh * 64 * Lq;

  bf16* ldsK0 = KB + (size_t)(w * 64) * 8;
  bf16* ldsK1 = KB + (size_t)(256 + w * 64) * 8;
  bf16* ldsV0 = VB + (size_t)(w * 64) * 8;
  bf16* ldsV1 = VB + (size_t)(256 + w * 64) * 8;
  const int w8 = w * 8;

  for (int half = 0; half < 2; ++half) {
    const int qt = (half == 0) ? (31 - pid) : pid;
    const int ql = qt * 64 + w * 16 + l16;
    const bf16x8 aq0 = ld8(Qp + (size_t)ql * LDL + quad * 8);
    const bf16x8 aq1 = ld8(Qp + (size_t)ql * LDL + 32 + quad * 8);

    f32x4 o_acc[4];
#pragma unroll
    for (int d = 0; d < 4; d++)
#pragma unroll
      for (int r = 0; r < 4; r++) o_acc[d][r] = 0.f;
    float m_run = -3e30f, l_run = 0.f;

    for (int kt = 0; kt <= qt; ++kt) {
      const size_t kb = (size_t)kt * 64;

      async_lds16(Kp + (size_t)(kb + lane) * LDL + w8, ldsK0);
      async_lds16(Kp + (size_t)(kb + lane) * LDL + 32 + w8, ldsK1);
      async_lds16(Vp + (size_t)lane * Lq + kb + w8, ldsV0);
      async_lds16(Vp + (size_t)lane * Lq + kb + 32 + w8, ldsV1);
      __syncthreads();

      f32x4 s[4];
#pragma unroll
      for (int ks = 0; ks < 4; ks++) {
        const bf16x8 kc0 = ld8(&KB[(size_t)((quad)*64 + ks * 16 + l16) * 8]);
        const bf16x8 kc1 = ld8(&KB[(size_t)((4 + quad) * 64 + ks * 16 + l16) * 8]);
#pragma unroll
        for (int r = 0; r < 4; r++) s[ks][r] = 0.f;
        s[ks] = __builtin_amdgcn_mfma_f32_16x16x32_bf16(kc0, aq0, s[ks], 0, 0, 0);
        s[ks] = __builtin_amdgcn_mfma_f32_16x16x32_bf16(kc1, aq1, s[ks], 0, 0, 0);
      }

      if (kt == qt) {
#pragma unroll
        for (int ks = 0; ks < 4; ks++) {
#pragma unroll
          for (int r = 0; r < 4; r++) {
            const int kg = kt * 64 + ks * 16 + quad * 4 + r;
            if (kg > ql) s[ks][r] = -14427.0f;
          }
        }
      }

      float tmax = s[0][0];
#pragma unroll
      for (int ks = 0; ks < 4; ks++)
#pragma unroll
        for (int r = 0; r < 4; r++) tmax = fmaxf(tmax, s[ks][r]);
      tmax = fmaxf(tmax, __shfl_xor(tmax, 16, 64));
      tmax = fmaxf(tmax, __shfl_xor(tmax, 32, 64));
      const float mnew = fmaxf(m_run, tmax);
      const float alpha = exp2f(m_run - mnew);
      m_run = mnew;
      float rsum = 0.f;
      short4v pf[4];
#pragma unroll
      for (int ks = 0; ks < 4; ks++) {
#pragma unroll
        for (int r = 0; r < 4; r++) {
          const float pv = exp2f(s[ks][r] - mnew);
          rsum += pv;
          pf[ks][r] = bfbits(pv);
        }
      }
      rsum += __shfl_xor(rsum, 16, 64);
      rsum += __shfl_xor(rsum, 32, 64);
      l_run = l_run * alpha + rsum;
#pragma unroll
      for (int d = 0; d < 4; d++)
#pragma unroll
        for (int r = 0; r < 4; r++) o_acc[d][r] *= alpha;

#pragma unroll
      for (int d = 0; d < 4; d++) {
#pragma unroll
        for (int ks = 0; ks < 4; ks++) {
          const int g = ks * 2 + (quad >> 1);
          const short4v av =
              *(const short4v*)&VB[(size_t)(g * 64 + d * 16 + l16) * 8 + (quad & 1) * 4];
          o_acc[d] = __builtin_amdgcn_mfma_f32_16x16x16bf16_1k(av, pf[ks], o_acc[d], 0, 0, 0);
        }
      }
      __syncthreads();
    }

    const float inv_l = 1.f / fmaxf(l_run, 1e-30f);
    const size_t obase = (size_t)ql * (Nb * E) + (size_t)n * E + h * Dd;
#pragma unroll
    for (int d = 0; d < 4; d++)
#pragma unroll
      for (int r = 0; r < 4; r++)
        O[obase + d * 16 + quad * 4 + r] = __float2bfloat16(o_acc[d][r] * inv_l);
  }
}

// ---------------------------------------------------------------------------
extern "C" void kernel_launch(void* const* d_in, const int* in_sizes, int n_in,
                              void* d_out, int out_size, void* d_ws, size_t ws_size,
                              hipStream_t stream) {
  const float* x    = (const float*)d_in[0];
  const float* ln1w = (const float*)d_in[1];
  const float* ln1b = (const float*)d_in[2];
  const float* wq   = (const float*)d_in[3];
  const float* bq   = (const float*)d_in[4];
  const float* wk   = (const float*)d_in[5];
  const float* bk   = (const float*)d_in[6];
  const float* wv   = (const float*)d_in[7];
  const float* bv   = (const float*)d_in[8];
  const float* wout = (const float*)d_in[9];
  const float* bout = (const float*)d_in[10];
  const float* ln2w = (const float*)d_in[11];
  const float* ln2b = (const float*)d_in[12];
  const float* fc1w = (const float*)d_in[13];
  const float* fc1b = (const float*)d_in[14];
  const float* fc2w = (const float*)d_in[15];
  const float* fc2b = (const float*)d_in[16];

  char* ws = (char*)d_ws;
  bf16* wqkvb = (bf16*)(ws);                        // 0-6 MB  [wq;wk;wv]
  bf16* woutb = (bf16*)(ws + ((size_t)6 << 20));    // 6-8 MB
  bf16* f1wb  = (bf16*)(ws + ((size_t)8 << 20));    // 8-16 MB
  bf16* f2wb  = (bf16*)(ws + ((size_t)16 << 20));   // 16-24 MB
  bf16* h1    = (bf16*)(ws + ((size_t)24 << 20));   // 24-32 MB (h2 reuses)
  bf16* qk    = (bf16*)(ws + ((size_t)32 << 20));   // 32-48 MB [4096][2048]
  bf16* vtg   = (bf16*)(ws + ((size_t)48 << 20));   // 48-56 MB V^T [32*64][2048]
  bf16* o     = (bf16*)(ws + ((size_t)56 << 20));   // 56-64 MB
  float* x1   = (float*)(ws + ((size_t)64 << 20));  // 64-80 MB f32
  bf16* Pout  = (bf16*)(ws + ((size_t)32 << 20));   // 32-48: out-proj splitK
  bf16* P01   = (bf16*)(ws);                        // 0-16: FC2 splitK partials
  bf16* f1    = (bf16*)(ws + ((size_t)32 << 20));   // 32-64 (qk,vtg,o dead)
  bf16* h2    = h1;
  float* outp = (float*)d_out;

  cvt_all_kernel<<<12288, 256, 0, stream>>>(wq, wk, wv, wout, fc1w, fc2w,
                                            wqkvb, woutb, f1wb, f2wb);

  ln_kernel<<<MT, 256, 0, stream>>>(x, ln1w, ln1b, h1);

  dim3 gQKV(3 * E / 128, MT / 128);   // (24,32)
  dim3 gE2(E / 128, MT / 128, 2);     // (8,32,2) split-K
  dim3 gF(Ff / 128, MT / 128);        // (32,32)

  // q pre-scale folded with log2(e) for exp2-domain softmax
  gemm_bt<4><<<gQKV, 256, 0, stream>>>(h1, wqkvb, bq, bk, bv, E, E, 2048,
                                       0.125f * 1.44269504f, 1024, qk, vtg);

  attn_kernel<<<dim3(16, Nb * Hh), 256, 0, stream>>>(qk, vtg, o);

  gemm_bt<3><<<gE2, 256, 0, stream>>>(o, woutb, nullptr, nullptr, nullptr,
                                      E / 2, E, E, 1.f, 0, Pout, nullptr);
  redln_kernel<<<MT, 256, 0, stream>>>(Pout, bout, x, ln2w, ln2b, x1, h2);

  gemm_bt<2><<<gF, 256, 0, stream>>>(h2, f1wb, fc1b, nullptr, nullptr, E, E, Ff,
                                     1.f, 0, f1, nullptr);

  gemm_bt<3><<<gE2, 256, 0, stream>>>(f1, f2wb, nullptr, nullptr, nullptr,
                                      Ff / 2, Ff, E, 1.f, 0, P01, nullptr);
  reduce2_kernel<<<MT * E / 1024, 256, 0, stream>>>(P01, fc2b, x1, outp);
}

// Round 12
// 380.859 us; speedup vs baseline: 1.0834x; 1.0834x over previous
//
#include <hip/hip_runtime.h>
#include <hip/hip_bf16.h>
#include <math.h>

using bf16 = __hip_bfloat16;
typedef __bf16 bf16x8 __attribute__((ext_vector_type(8)));
typedef short  short4v __attribute__((ext_vector_type(4)));
typedef float  f32x4  __attribute__((ext_vector_type(4)));

static constexpr int Lq = 2048, Nb = 2, E = 1024, Hh = 16, Dd = 64, Ff = 4096;
static constexpr int MT = Lq * Nb;          // 4096 tokens
static constexpr int QKLD = 2 * E;          // 2048: q|k row stride per token
static constexpr int LDL = 2 * QKLD;        // 4096: stride per seq-step l

__device__ __forceinline__ void async_lds16(const void* g, void* l) {
  __builtin_amdgcn_global_load_lds(
      (const __attribute__((address_space(1))) void*)g,
      (__attribute__((address_space(3))) void*)l, 16, 0, 0);
}
__device__ __forceinline__ bf16x8 ld8(const bf16* p) { return *(const bf16x8*)p; }
__device__ __forceinline__ short bfbits(float x) {
  bf16 t = __float2bfloat16(x);
  return *(short*)&t;
}
// fast gelu (tanh form, reduced): gelu(v) = v * t/(t+1),
// t = exp2(2.302208*(v + 0.044715 v^3)); max abs err ~1e-3
__device__ __forceinline__ float gelu_fast(float v) {
  const float y = fminf(2.302208f * (v + 0.044715f * v * v * v), 80.f);
  const float t = exp2f(y);
  return v * t / (t + 1.0f);
}

// ---------------------------------------------------------------------------
// Fused f32 -> bf16 cast of all 6 weight matrices in ONE dispatch.
// ---------------------------------------------------------------------------
__global__ __launch_bounds__(256) void cvt_all_kernel(
    const float* __restrict__ wq, const float* __restrict__ wk,
    const float* __restrict__ wv, const float* __restrict__ wout,
    const float* __restrict__ fc1w, const float* __restrict__ fc2w,
    bf16* __restrict__ wqkvb, bf16* __restrict__ woutb,
    bf16* __restrict__ f1wb, bf16* __restrict__ f2wb) {
  const int i = blockIdx.x * 256 + threadIdx.x;
  const float* src;
  bf16* dst;
  size_t off;
  if (i < 786432) {            // qkv: three E*E blocks concat in wqkvb
    const int r = i >> 18;     // 0,1,2
    off = (size_t)(i & 262143);
    src = (r == 0) ? wq : (r == 1) ? wk : wv;
    dst = wqkvb + (size_t)r * (E * E);
  } else if (i < 1048576) {
    off = (size_t)(i - 786432); src = wout; dst = woutb;
  } else if (i < 2097152) {
    off = (size_t)(i - 1048576); src = fc1w; dst = f1wb;
  } else {
    off = (size_t)(i - 2097152); src = fc2w; dst = f2wb;
  }
  float4 v = ((const float4*)src)[off];
  bf16 o4[4] = {__float2bfloat16(v.x), __float2bfloat16(v.y),
                __float2bfloat16(v.z), __float2bfloat16(v.w)};
  *(uint2*)(dst + 4 * off) = *(uint2*)o4;
}

// ---------------------------------------------------------------------------
// GEMM, templated on BK (32 = R9-proven body; 64 = R10-proven XOR-swizzled
// body, measured faster for QKV/split-K shapes; 32 measured faster for FC1).
// C[m][n] = sum_k A[m][k]*W[n][k]; 128x128 tile, 4 waves 2x2.
// EPI 2: gelu_fast(acc+bias) -> bf16
// EPI 3: acc -> bf16 partial at z*MT*E (split-K, no bias)
// EPI 4: QKV: ncol<2048 -> outb[token][2048]; ncol>=2048 -> V^T scatter
// ---------------------------------------------------------------------------
template <int EPI, int BK>
__global__ __launch_bounds__(256) void gemm_bt(
    const bf16* __restrict__ A, const bf16* __restrict__ W,
    const float* __restrict__ b1, const float* __restrict__ b2,
    const float* __restrict__ b3, int Klen, int Kstride, int Nld,
    float qscale, int scut, bf16* __restrict__ outb,
    bf16* __restrict__ outv) {
  __shared__ __align__(16) bf16 As[128 * BK];
  __shared__ __align__(16) bf16 Bs[128 * BK];
  const int tid = threadIdx.x;
  const int w = tid >> 6, lane = tid & 63;
  const int quad = lane >> 4, l16 = lane & 15;
  const int wm = (w >> 1) * 64, wn = (w & 1) * 64;
  const int m0 = blockIdx.y * 128, n0 = blockIdx.x * 128;
  const int koff = blockIdx.z * Klen;

  f32x4 acc[4][4];
#pragma unroll
  for (int i = 0; i < 4; i++)
#pragma unroll
    for (int j = 0; j < 4; j++)
#pragma unroll
      for (int r = 0; r < 4; r++) acc[i][j][r] = 0.f;

  if constexpr (BK == 32) {
    const int c0 = w * 64 + lane;
    const int c1 = c0 + 256;
    const size_t arow0 = (size_t)(m0 + (c0 >> 2)), arow1 = (size_t)(m0 + (c1 >> 2));
    const size_t brow0 = (size_t)(n0 + (c0 >> 2)), brow1 = (size_t)(n0 + (c1 >> 2));
    const int col0 = (c0 & 3) * 8, col1 = (c1 & 3) * 8;
    bf16* ldsA0 = &As[(w * 64) * 8];
    bf16* ldsA1 = &As[(256 + w * 64) * 8];
    bf16* ldsB0 = &Bs[(w * 64) * 8];
    bf16* ldsB1 = &Bs[(256 + w * 64) * 8];

    const int nk = Klen >> 5;
    for (int kt = 0; kt < nk; ++kt) {
      const int k0 = koff + kt * 32;
      async_lds16(A + arow0 * Kstride + k0 + col0, ldsA0);
      async_lds16(A + arow1 * Kstride + k0 + col1, ldsA1);
      async_lds16(W + brow0 * Kstride + k0 + col0, ldsB0);
      async_lds16(W + brow1 * Kstride + k0 + col1, ldsB1);
      __syncthreads();
      bf16x8 a[4], b[4];
#pragma unroll
      for (int i = 0; i < 4; i++) {
        a[i] = ld8(&As[(wm + i * 16 + l16) * 32 + quad * 8]);
        b[i] = ld8(&Bs[(wn + i * 16 + l16) * 32 + quad * 8]);
      }
#pragma unroll
      for (int i = 0; i < 4; i++)
#pragma unroll
        for (int j = 0; j < 4; j++)
          acc[i][j] = __builtin_amdgcn_mfma_f32_16x16x32_bf16(a[i], b[j], acc[i][j], 0, 0, 0);
      __syncthreads();
    }
  } else {  // BK == 64, XOR-swizzled (0 bank conflicts, R10-measured)
    const int rowoff = w * 8 + (lane >> 3);
    const int colsw = (((lane & 7) ^ (lane >> 3)) << 3);

    const int nk = Klen >> 6;
    for (int kt = 0; kt < nk; ++kt) {
      const int k0 = koff + (kt << 6);
#pragma unroll
      for (int r = 0; r < 4; r++) {
        async_lds16(A + (size_t)(m0 + r * 32 + rowoff) * Kstride + k0 + colsw,
                    As + (size_t)(r * 256 + w * 64) * 8);
        async_lds16(W + (size_t)(n0 + r * 32 + rowoff) * Kstride + k0 + colsw,
                    Bs + (size_t)(r * 256 + w * 64) * 8);
      }
      __syncthreads();
#pragma unroll
      for (int ksub = 0; ksub < 2; ksub++) {
        const int gx = ksub * 4 + quad;
        bf16x8 a[4], b[4];
#pragma unroll
        for (int i = 0; i < 4; i++) {
          const int ra = wm + i * 16 + l16;
          const int rb = wn + i * 16 + l16;
          a[i] = ld8(&As[(size_t)(ra * 8 + (gx ^ (l16 & 7))) * 8]);
          b[i] = ld8(&Bs[(size_t)(rb * 8 + (gx ^ (l16 & 7))) * 8]);
        }
#pragma unroll
        for (int i = 0; i < 4; i++)
#pragma unroll
          for (int j = 0; j < 4; j++)
            acc[i][j] = __builtin_amdgcn_mfma_f32_16x16x32_bf16(a[i], b[j], acc[i][j], 0, 0, 0);
      }
      __syncthreads();
    }
  }

  const size_t zoff = (EPI == 3) ? (size_t)blockIdx.z * ((size_t)MT * E) : 0;
#pragma unroll
  for (int i = 0; i < 4; i++) {
    const int mrow = m0 + wm + i * 16 + quad * 4;
#pragma unroll
    for (int j = 0; j < 4; j++) {
      const int ncol = n0 + wn + j * 16 + l16;
      float bv = 0.f;
      if constexpr (EPI != 3) {
        if (b3 != nullptr) {
          bv = (ncol < 1024) ? b1[ncol]
               : (ncol < 2048) ? b2[ncol - 1024] : b3[ncol - 2048];
        } else {
          bv = b1[ncol];
        }
      }
      const float sc = (ncol < scut) ? qscale : 1.0f;
#pragma unroll
      for (int r = 0; r < 4; r++) {
        float v = (acc[i][j][r] + bv) * sc;
        if constexpr (EPI == 2) {
          outb[(size_t)(mrow + r) * Nld + ncol] = __float2bfloat16(gelu_fast(v));
        } else if constexpr (EPI == 3) {
          outb[zoff + (size_t)(mrow + r) * Nld + ncol] = __float2bfloat16(v);
        } else {  // EPI 4: QKV
          if (ncol < 2048) {
            outb[(size_t)(mrow + r) * 2048 + ncol] = __float2bfloat16(v);
          } else {
            const int h = (ncol - 2048) >> 6, d = ncol & 63;
            const int tok = mrow + r, n = tok & 1, l = tok >> 1;
            outv[(size_t)((n * 16 + h) * 64 + d) * Lq + l] = __float2bfloat16(v);
          }
        }
      }
    }
  }
}

// ---------------------------------------------------------------------------
// Split-K reduce: out[i] = P0[i] + P1[i] + bias[col] + res[i]   (f32 out)
// ---------------------------------------------------------------------------
__global__ __launch_bounds__(256) void reduce2_kernel(
    const bf16* __restrict__ P, const float* __restrict__ bias,
    const float* __restrict__ res, float* __restrict__ out) {
  const int i = blockIdx.x * 256 + threadIdx.x;  // float4 index
  const size_t e0 = (size_t)i * 4;
  const int col = (int)(e0 & (E - 1));
  uint2 u0 = *(const uint2*)(P + e0);
  uint2 u1 = *(const uint2*)(P + (size_t)MT * E + e0);
  const bf16* p0 = (const bf16*)&u0;
  const bf16* p1 = (const bf16*)&u1;
  float4 b = *(const float4*)(bias + col);
  float4 r = *(const float4*)(res + e0);
  float4 o;
  o.x = (float)p0[0] + (float)p1[0] + b.x + r.x;
  o.y = (float)p0[1] + (float)p1[1] + b.y + r.y;
  o.z = (float)p0[2] + (float)p1[2] + b.z + r.z;
  o.w = (float)p0[3] + (float)p1[3] + b.w + r.w;
  *(float4*)(out + e0) = o;
}

// ---------------------------------------------------------------------------
// Fused out-proj reduce + LayerNorm2. One block per token.
// ---------------------------------------------------------------------------
__global__ __launch_bounds__(256) void redln_kernel(
    const bf16* __restrict__ P, const float* __restrict__ bias,
    const float* __restrict__ res, const float* __restrict__ wgt,
    const float* __restrict__ bia, float* __restrict__ x1,
    bf16* __restrict__ h2) {
  const int t = blockIdx.x, tid = threadIdx.x;
  const size_t base = (size_t)t * E;
  const int e0 = tid * 4;
  uint2 u0 = *(const uint2*)(P + base + e0);
  uint2 u1 = *(const uint2*)(P + (size_t)MT * E + base + e0);
  const bf16* p0 = (const bf16*)&u0;
  const bf16* p1 = (const bf16*)&u1;
  float4 b = *(const float4*)(bias + e0);
  float4 r = *(const float4*)(res + base + e0);
  float v4[4];
  v4[0] = (float)p0[0] + (float)p1[0] + b.x + r.x;
  v4[1] = (float)p0[1] + (float)p1[1] + b.y + r.y;
  v4[2] = (float)p0[2] + (float)p1[2] + b.z + r.z;
  v4[3] = (float)p0[3] + (float)p1[3] + b.w + r.w;
  *(float4*)(x1 + base + e0) = *(float4*)v4;

  float s = 0.f, ss = 0.f;
#pragma unroll
  for (int i = 0; i < 4; i++) { s += v4[i]; ss += v4[i] * v4[i]; }
  for (int off = 32; off > 0; off >>= 1) {
    s += __shfl_down(s, off, 64);
    ss += __shfl_down(ss, off, 64);
  }
  __shared__ float rs[4], rss[4], mv[2];
  const int w = tid >> 6;
  if ((tid & 63) == 0) { rs[w] = s; rss[w] = ss; }
  __syncthreads();
  if (tid == 0) {
    float S = rs[0] + rs[1] + rs[2] + rs[3];
    float SS = rss[0] + rss[1] + rss[2] + rss[3];
    float mean = S * (1.f / E);
    float var = SS * (1.f / E) - mean * mean;
    mv[0] = mean; mv[1] = rsqrtf(var + 1e-5f);
  }
  __syncthreads();
  const float mean = mv[0], rstd = mv[1];
  float4 wg = *(const float4*)(wgt + e0);
  float4 bb = *(const float4*)(bia + e0);
  bf16 o4[4];
  o4[0] = __float2bfloat16((v4[0] - mean) * rstd * wg.x + bb.x);
  o4[1] = __float2bfloat16((v4[1] - mean) * rstd * wg.y + bb.y);
  o4[2] = __float2bfloat16((v4[2] - mean) * rstd * wg.z + bb.z);
  o4[3] = __float2bfloat16((v4[3] - mean) * rstd * wg.w + bb.w);
  *(uint2*)(h2 + base + e0) = *(uint2*)o4;
}

// ---------------------------------------------------------------------------
// LayerNorm over E=1024 per token (f32 in, bf16 out). One block per token.
// ---------------------------------------------------------------------------
__global__ __launch_bounds__(256) void ln_kernel(
    const float* __restrict__ x, const float* __restrict__ wgt,
    const float* __restrict__ bia, bf16* __restrict__ out) {
  const int t = blockIdx.x, tid = threadIdx.x;
  const size_t base = (size_t)t * E;
  float v4[4], s = 0.f, ss = 0.f;
#pragma unroll
  for (int i = 0; i < 4; i++) {
    float v = x[base + i * 256 + tid];
    v4[i] = v; s += v; ss += v * v;
  }
  for (int off = 32; off > 0; off >>= 1) {
    s += __shfl_down(s, off, 64);
    ss += __shfl_down(ss, off, 64);
  }
  __shared__ float rs[4], rss[4], mv[2];
  const int w = tid >> 6;
  if ((tid & 63) == 0) { rs[w] = s; rss[w] = ss; }
  __syncthreads();
  if (tid == 0) {
    float S = rs[0] + rs[1] + rs[2] + rs[3];
    float SS = rss[0] + rss[1] + rss[2] + rss[3];
    float mean = S * (1.f / E);
    float var = SS * (1.f / E) - mean * mean;
    mv[0] = mean; mv[1] = rsqrtf(var + 1e-5f);
  }
  __syncthreads();
  const float mean = mv[0], rstd = mv[1];
#pragma unroll
  for (int i = 0; i < 4; i++) {
    const int e = i * 256 + tid;
    float r = (v4[i] - mean) * rstd * wgt[e] + bia[e];
    out[base + e] = __float2bfloat16(r);
  }
}

// ---------------------------------------------------------------------------
// Flash attention v8: v7 body + XCD-aware block swizzle. 1-D grid 512.
// Decode: x=bid%8, inner=bid/8, pid=inner%16, hh=(inner/16)*8+x  -> all 16
// pid-blocks of head hh share bid%8 (same XCD if round-robin), keeping the
// head's 512 KB K/V set in one XCD's 4 MB L2.
// ---------------------------------------------------------------------------
__global__ __launch_bounds__(256) void attn_kernel(
    const bf16* __restrict__ QK, const bf16* __restrict__ VT,
    bf16* __restrict__ O) {
  __shared__ __align__(16) bf16 KB[512 * 8];  // 8 KB
  __shared__ __align__(16) bf16 VB[512 * 8];  // 8 KB
  const int tid = threadIdx.x;
  const int w = tid >> 6, lane = tid & 63, quad = lane >> 4, l16 = lane & 15;
  const int bid = blockIdx.x;          // 0..511
  const int xcd = bid & 7;
  const int inner = bid >> 3;
  const int pid = inner & 15;          // 0..15
  const int hh = ((inner >> 4) << 3) | xcd;  // 0..31
  const int n = hh >> 4, h = hh & 15;

  const bf16* Qp = QK + n * QKLD + h * Dd;
  const bf16* Kp = Qp + E;
  const bf16* Vp = VT + (size_t)hh * 64 * Lq;

  bf16* ldsK0 = KB + (size_t)(w * 64) * 8;
  bf16* ldsK1 = KB + (size_t)(256 + w * 64) * 8;
  bf16* ldsV0 = VB + (size_t)(w * 64) * 8;
  bf16* ldsV1 = VB + (size_t)(256 + w * 64) * 8;
  const int w8 = w * 8;

  for (int half = 0; half < 2; ++half) {
    const int qt = (half == 0) ? (31 - pid) : pid;
    const int ql = qt * 64 + w * 16 + l16;
    const bf16x8 aq0 = ld8(Qp + (size_t)ql * LDL + quad * 8);
    const bf16x8 aq1 = ld8(Qp + (size_t)ql * LDL + 32 + quad * 8);

    f32x4 o_acc[4];
#pragma unroll
    for (int d = 0; d < 4; d++)
#pragma unroll
      for (int r = 0; r < 4; r++) o_acc[d][r] = 0.f;
    float m_run = -3e30f, l_run = 0.f;

    for (int kt = 0; kt <= qt; ++kt) {
      const size_t kb = (size_t)kt * 64;

      async_lds16(Kp + (size_t)(kb + lane) * LDL + w8, ldsK0);
      async_lds16(Kp + (size_t)(kb + lane) * LDL + 32 + w8, ldsK1);
      async_lds16(Vp + (size_t)lane * Lq + kb + w8, ldsV0);
      async_lds16(Vp + (size_t)lane * Lq + kb + 32 + w8, ldsV1);
      __syncthreads();

      f32x4 s[4];
#pragma unroll
      for (int ks = 0; ks < 4; ks++) {
        const bf16x8 kc0 = ld8(&KB[(size_t)((quad)*64 + ks * 16 + l16) * 8]);
        const bf16x8 kc1 = ld8(&KB[(size_t)((4 + quad) * 64 + ks * 16 + l16) * 8]);
#pragma unroll
        for (int r = 0; r < 4; r++) s[ks][r] = 0.f;
        s[ks] = __builtin_amdgcn_mfma_f32_16x16x32_bf16(kc0, aq0, s[ks], 0, 0, 0);
        s[ks] = __builtin_amdgcn_mfma_f32_16x16x32_bf16(kc1, aq1, s[ks], 0, 0, 0);
      }

      if (kt == qt) {
#pragma unroll
        for (int ks = 0; ks < 4; ks++) {
#pragma unroll
          for (int r = 0; r < 4; r++) {
            const int kg = kt * 64 + ks * 16 + quad * 4 + r;
            if (kg > ql) s[ks][r] = -14427.0f;
          }
        }
      }

      float tmax = s[0][0];
#pragma unroll
      for (int ks = 0; ks < 4; ks++)
#pragma unroll
        for (int r = 0; r < 4; r++) tmax = fmaxf(tmax, s[ks][r]);
      tmax = fmaxf(tmax, __shfl_xor(tmax, 16, 64));
      tmax = fmaxf(tmax, __shfl_xor(tmax, 32, 64));
      const float mnew = fmaxf(m_run, tmax);
      const float alpha = exp2f(m_run - mnew);
      m_run = mnew;
      float rsum = 0.f;
      short4v pf[4];
#pragma unroll
      for (int ks = 0; ks < 4; ks++) {
#pragma unroll
        for (int r = 0; r < 4; r++) {
          const float pv = exp2f(s[ks][r] - mnew);
          rsum += pv;
          pf[ks][r] = bfbits(pv);
        }
      }
      rsum += __shfl_xor(rsum, 16, 64);
      rsum += __shfl_xor(rsum, 32, 64);
      l_run = l_run * alpha + rsum;
#pragma unroll
      for (int d = 0; d < 4; d++)
#pragma unroll
        for (int r = 0; r < 4; r++) o_acc[d][r] *= alpha;

#pragma unroll
      for (int d = 0; d < 4; d++) {
#pragma unroll
        for (int ks = 0; ks < 4; ks++) {
          const int g = ks * 2 + (quad >> 1);
          const short4v av =
              *(const short4v*)&VB[(size_t)(g * 64 + d * 16 + l16) * 8 + (quad & 1) * 4];
          o_acc[d] = __builtin_amdgcn_mfma_f32_16x16x16bf16_1k(av, pf[ks], o_acc[d], 0, 0, 0);
        }
      }
      __syncthreads();
    }

    const float inv_l = 1.f / fmaxf(l_run, 1e-30f);
    const size_t obase = (size_t)ql * (Nb * E) + (size_t)n * E + h * Dd;
#pragma unroll
    for (int d = 0; d < 4; d++)
#pragma unroll
      for (int r = 0; r < 4; r++)
        O[obase + d * 16 + quad * 4 + r] = __float2bfloat16(o_acc[d][r] * inv_l);
  }
}

// ---------------------------------------------------------------------------
extern "C" void kernel_launch(void* const* d_in, const int* in_sizes, int n_in,
                              void* d_out, int out_size, void* d_ws, size_t ws_size,
                              hipStream_t stream) {
  const float* x    = (const float*)d_in[0];
  const float* ln1w = (const float*)d_in[1];
  const float* ln1b = (const float*)d_in[2];
  const float* wq   = (const float*)d_in[3];
  const float* bq   = (const float*)d_in[4];
  const float* wk   = (const float*)d_in[5];
  const float* bk   = (const float*)d_in[6];
  const float* wv   = (const float*)d_in[7];
  const float* bv   = (const float*)d_in[8];
  const float* wout = (const float*)d_in[9];
  const float* bout = (const float*)d_in[10];
  const float* ln2w = (const float*)d_in[11];
  const float* ln2b = (const float*)d_in[12];
  const float* fc1w = (const float*)d_in[13];
  const float* fc1b = (const float*)d_in[14];
  const float* fc2w = (const float*)d_in[15];
  const float* fc2b = (const float*)d_in[16];

  char* ws = (char*)d_ws;
  bf16* wqkvb = (bf16*)(ws);                        // 0-6 MB  [wq;wk;wv]
  bf16* woutb = (bf16*)(ws + ((size_t)6 << 20));    // 6-8 MB
  bf16* f1wb  = (bf16*)(ws + ((size_t)8 << 20));    // 8-16 MB
  bf16* f2wb  = (bf16*)(ws + ((size_t)16 << 20));   // 16-24 MB
  bf16* h1    = (bf16*)(ws + ((size_t)24 << 20));   // 24-32 MB (h2 reuses)
  bf16* qk    = (bf16*)(ws + ((size_t)32 << 20));   // 32-48 MB [4096][2048]
  bf16* vtg   = (bf16*)(ws + ((size_t)48 << 20));   // 48-56 MB V^T [32*64][2048]
  bf16* o     = (bf16*)(ws + ((size_t)56 << 20));   // 56-64 MB
  float* x1   = (float*)(ws + ((size_t)64 << 20));  // 64-80 MB f32
  bf16* Pout  = (bf16*)(ws + ((size_t)32 << 20));   // 32-48: out-proj splitK
  bf16* P01   = (bf16*)(ws);                        // 0-16: FC2 splitK partials
  bf16* f1    = (bf16*)(ws + ((size_t)32 << 20));   // 32-64 (qk,vtg,o dead)
  bf16* h2    = h1;
  float* outp = (float*)d_out;

  cvt_all_kernel<<<12288, 256, 0, stream>>>(wq, wk, wv, wout, fc1w, fc2w,
                                            wqkvb, woutb, f1wb, f2wb);

  ln_kernel<<<MT, 256, 0, stream>>>(x, ln1w, ln1b, h1);

  dim3 gQKV(3 * E / 128, MT / 128);   // (24,32)
  dim3 gE2(E / 128, MT / 128, 2);     // (8,32,2) split-K
  dim3 gF(Ff / 128, MT / 128);        // (32,32)

  // q pre-scale folded with log2(e) for exp2-domain softmax
  gemm_bt<4, 64><<<gQKV, 256, 0, stream>>>(h1, wqkvb, bq, bk, bv, E, E, 2048,
                                           0.125f * 1.44269504f, 1024, qk, vtg);

  attn_kernel<<<512, 256, 0, stream>>>(qk, vtg, o);

  gemm_bt<3, 64><<<gE2, 256, 0, stream>>>(o, woutb, nullptr, nullptr, nullptr,
                                          E / 2, E, E, 1.f, 0, Pout, nullptr);
  redln_kernel<<<MT, 256, 0, stream>>>(Pout, bout, x, ln2w, ln2b, x1, h2);

  gemm_bt<2, 32><<<gF, 256, 0, stream>>>(h2, f1wb, fc1b, nullptr, nullptr,
                                         E, E, Ff, 1.f, 0, f1, nullptr);

  gemm_bt<3, 64><<<gE2, 256, 0, stream>>>(f1, f2wb, nullptr, nullptr, nullptr,
                                          Ff / 2, Ff, E, 1.f, 0, P01, nullptr);
  reduce2_kernel<<<MT * E / 1024, 256, 0, stream>>>(P01, fc2b, x1, outp);
}

// Round 13
// 379.137 us; speedup vs baseline: 1.0883x; 1.0045x over previous
//
#include <hip/hip_runtime.h>
#include <hip/hip_bf16.h>
#include <math.h>

using bf16 = __hip_bfloat16;
typedef __bf16 bf16x8 __attribute__((ext_vector_type(8)));
typedef short  short4v __attribute__((ext_vector_type(4)));
typedef float  f32x4  __attribute__((ext_vector_type(4)));

static constexpr int Lq = 2048, Nb = 2, E = 1024, Hh = 16, Dd = 64, Ff = 4096;
static constexpr int MT = Lq * Nb;          // 4096 tokens
static constexpr int QKLD = 2 * E;          // 2048: q|k row stride per token
static constexpr int LDL = 2 * QKLD;        // 4096: stride per seq-step l

__device__ __forceinline__ void async_lds16(const void* g, void* l) {
  __builtin_amdgcn_global_load_lds(
      (const __attribute__((address_space(1))) void*)g,
      (__attribute__((address_space(3))) void*)l, 16, 0, 0);
}
__device__ __forceinline__ bf16x8 ld8(const bf16* p) { return *(const bf16x8*)p; }
__device__ __forceinline__ short bfbits(float x) {
  bf16 t = __float2bfloat16(x);
  return *(short*)&t;
}
// fast gelu (tanh form, reduced): gelu(v) = v * t/(t+1),
// t = exp2(2.302208*(v + 0.044715 v^3)); max abs err ~1e-3
__device__ __forceinline__ float gelu_fast(float v) {
  const float y = fminf(2.302208f * (v + 0.044715f * v * v * v), 80.f);
  const float t = exp2f(y);
  return v * t / (t + 1.0f);
}

// ---------------------------------------------------------------------------
// Fused f32 -> bf16 cast of all 6 weight matrices in ONE dispatch.
// ---------------------------------------------------------------------------
__global__ __launch_bounds__(256) void cvt_all_kernel(
    const float* __restrict__ wq, const float* __restrict__ wk,
    const float* __restrict__ wv, const float* __restrict__ wout,
    const float* __restrict__ fc1w, const float* __restrict__ fc2w,
    bf16* __restrict__ wqkvb, bf16* __restrict__ woutb,
    bf16* __restrict__ f1wb, bf16* __restrict__ f2wb) {
  const int i = blockIdx.x * 256 + threadIdx.x;
  const float* src;
  bf16* dst;
  size_t off;
  if (i < 786432) {            // qkv: three E*E blocks concat in wqkvb
    const int r = i >> 18;     // 0,1,2
    off = (size_t)(i & 262143);
    src = (r == 0) ? wq : (r == 1) ? wk : wv;
    dst = wqkvb + (size_t)r * (E * E);
  } else if (i < 1048576) {
    off = (size_t)(i - 786432); src = wout; dst = woutb;
  } else if (i < 2097152) {
    off = (size_t)(i - 1048576); src = fc1w; dst = f1wb;
  } else {
    off = (size_t)(i - 2097152); src = fc2w; dst = f2wb;
  }
  float4 v = ((const float4*)src)[off];
  bf16 o4[4] = {__float2bfloat16(v.x), __float2bfloat16(v.y),
                __float2bfloat16(v.z), __float2bfloat16(v.w)};
  *(uint2*)(dst + 4 * off) = *(uint2*)o4;
}

// ---------------------------------------------------------------------------
// GEMM, templated on BK (32 = R9 body; 64 = R10 XOR-swizzled body).
// Measured: BK64 faster for QKV/split-K shapes, BK32 faster for FC1.
// EPI 2: gelu_fast(acc+bias) -> bf16
// EPI 3: acc -> bf16 partial at z*MT*E (split-K, no bias)
// EPI 4: QKV: ncol<2048 -> outb[token][2048]; ncol>=2048 -> V^T scatter
// ---------------------------------------------------------------------------
template <int EPI, int BK>
__global__ __launch_bounds__(256) void gemm_bt(
    const bf16* __restrict__ A, const bf16* __restrict__ W,
    const float* __restrict__ b1, const float* __restrict__ b2,
    const float* __restrict__ b3, int Klen, int Kstride, int Nld,
    float qscale, int scut, bf16* __restrict__ outb,
    bf16* __restrict__ outv) {
  __shared__ __align__(16) bf16 As[128 * BK];
  __shared__ __align__(16) bf16 Bs[128 * BK];
  const int tid = threadIdx.x;
  const int w = tid >> 6, lane = tid & 63;
  const int quad = lane >> 4, l16 = lane & 15;
  const int wm = (w >> 1) * 64, wn = (w & 1) * 64;
  const int m0 = blockIdx.y * 128, n0 = blockIdx.x * 128;
  const int koff = blockIdx.z * Klen;

  f32x4 acc[4][4];
#pragma unroll
  for (int i = 0; i < 4; i++)
#pragma unroll
    for (int j = 0; j < 4; j++)
#pragma unroll
      for (int r = 0; r < 4; r++) acc[i][j][r] = 0.f;

  if constexpr (BK == 32) {
    const int c0 = w * 64 + lane;
    const int c1 = c0 + 256;
    const size_t arow0 = (size_t)(m0 + (c0 >> 2)), arow1 = (size_t)(m0 + (c1 >> 2));
    const size_t brow0 = (size_t)(n0 + (c0 >> 2)), brow1 = (size_t)(n0 + (c1 >> 2));
    const int col0 = (c0 & 3) * 8, col1 = (c1 & 3) * 8;
    bf16* ldsA0 = &As[(w * 64) * 8];
    bf16* ldsA1 = &As[(256 + w * 64) * 8];
    bf16* ldsB0 = &Bs[(w * 64) * 8];
    bf16* ldsB1 = &Bs[(256 + w * 64) * 8];

    const int nk = Klen >> 5;
    for (int kt = 0; kt < nk; ++kt) {
      const int k0 = koff + kt * 32;
      async_lds16(A + arow0 * Kstride + k0 + col0, ldsA0);
      async_lds16(A + arow1 * Kstride + k0 + col1, ldsA1);
      async_lds16(W + brow0 * Kstride + k0 + col0, ldsB0);
      async_lds16(W + brow1 * Kstride + k0 + col1, ldsB1);
      __syncthreads();
      bf16x8 a[4], b[4];
#pragma unroll
      for (int i = 0; i < 4; i++) {
        a[i] = ld8(&As[(wm + i * 16 + l16) * 32 + quad * 8]);
        b[i] = ld8(&Bs[(wn + i * 16 + l16) * 32 + quad * 8]);
      }
#pragma unroll
      for (int i = 0; i < 4; i++)
#pragma unroll
        for (int j = 0; j < 4; j++)
          acc[i][j] = __builtin_amdgcn_mfma_f32_16x16x32_bf16(a[i], b[j], acc[i][j], 0, 0, 0);
      __syncthreads();
    }
  } else {  // BK == 64, XOR-swizzled (0 bank conflicts, R10-measured)
    const int rowoff = w * 8 + (lane >> 3);
    const int colsw = (((lane & 7) ^ (lane >> 3)) << 3);

    const int nk = Klen >> 6;
    for (int kt = 0; kt < nk; ++kt) {
      const int k0 = koff + (kt << 6);
#pragma unroll
      for (int r = 0; r < 4; r++) {
        async_lds16(A + (size_t)(m0 + r * 32 + rowoff) * Kstride + k0 + colsw,
                    As + (size_t)(r * 256 + w * 64) * 8);
        async_lds16(W + (size_t)(n0 + r * 32 + rowoff) * Kstride + k0 + colsw,
                    Bs + (size_t)(r * 256 + w * 64) * 8);
      }
      __syncthreads();
#pragma unroll
      for (int ksub = 0; ksub < 2; ksub++) {
        const int gx = ksub * 4 + quad;
        bf16x8 a[4], b[4];
#pragma unroll
        for (int i = 0; i < 4; i++) {
          const int ra = wm + i * 16 + l16;
          const int rb = wn + i * 16 + l16;
          a[i] = ld8(&As[(size_t)(ra * 8 + (gx ^ (l16 & 7))) * 8]);
          b[i] = ld8(&Bs[(size_t)(rb * 8 + (gx ^ (l16 & 7))) * 8]);
        }
#pragma unroll
        for (int i = 0; i < 4; i++)
#pragma unroll
          for (int j = 0; j < 4; j++)
            acc[i][j] = __builtin_amdgcn_mfma_f32_16x16x32_bf16(a[i], b[j], acc[i][j], 0, 0, 0);
      }
      __syncthreads();
    }
  }

  const size_t zoff = (EPI == 3) ? (size_t)blockIdx.z * ((size_t)MT * E) : 0;
#pragma unroll
  for (int i = 0; i < 4; i++) {
    const int mrow = m0 + wm + i * 16 + quad * 4;
#pragma unroll
    for (int j = 0; j < 4; j++) {
      const int ncol = n0 + wn + j * 16 + l16;
      float bv = 0.f;
      if constexpr (EPI != 3) {
        if (b3 != nullptr) {
          bv = (ncol < 1024) ? b1[ncol]
               : (ncol < 2048) ? b2[ncol - 1024] : b3[ncol - 2048];
        } else {
          bv = b1[ncol];
        }
      }
      const float sc = (ncol < scut) ? qscale : 1.0f;
#pragma unroll
      for (int r = 0; r < 4; r++) {
        float v = (acc[i][j][r] + bv) * sc;
        if constexpr (EPI == 2) {
          outb[(size_t)(mrow + r) * Nld + ncol] = __float2bfloat16(gelu_fast(v));
        } else if constexpr (EPI == 3) {
          outb[zoff + (size_t)(mrow + r) * Nld + ncol] = __float2bfloat16(v);
        } else {  // EPI 4: QKV
          if (ncol < 2048) {
            outb[(size_t)(mrow + r) * 2048 + ncol] = __float2bfloat16(v);
          } else {
            const int h = (ncol - 2048) >> 6, d = ncol & 63;
            const int tok = mrow + r, n = tok & 1, l = tok >> 1;
            outv[(size_t)((n * 16 + h) * 64 + d) * Lq + l] = __float2bfloat16(v);
          }
        }
      }
    }
  }
}

// ---------------------------------------------------------------------------
// Split-K reduce: out[i] = P0[i] + P1[i] + bias[col] + res[i]   (f32 out)
// ---------------------------------------------------------------------------
__global__ __launch_bounds__(256) void reduce2_kernel(
    const bf16* __restrict__ P, const float* __restrict__ bias,
    const float* __restrict__ res, float* __restrict__ out) {
  const int i = blockIdx.x * 256 + threadIdx.x;  // float4 index
  const size_t e0 = (size_t)i * 4;
  const int col = (int)(e0 & (E - 1));
  uint2 u0 = *(const uint2*)(P + e0);
  uint2 u1 = *(const uint2*)(P + (size_t)MT * E + e0);
  const bf16* p0 = (const bf16*)&u0;
  const bf16* p1 = (const bf16*)&u1;
  float4 b = *(const float4*)(bias + col);
  float4 r = *(const float4*)(res + e0);
  float4 o;
  o.x = (float)p0[0] + (float)p1[0] + b.x + r.x;
  o.y = (float)p0[1] + (float)p1[1] + b.y + r.y;
  o.z = (float)p0[2] + (float)p1[2] + b.z + r.z;
  o.w = (float)p0[3] + (float)p1[3] + b.w + r.w;
  *(float4*)(out + e0) = o;
}

// ---------------------------------------------------------------------------
// Fused out-proj reduce + LayerNorm2. One block per token.
// ---------------------------------------------------------------------------
__global__ __launch_bounds__(256) void redln_kernel(
    const bf16* __restrict__ P, const float* __restrict__ bias,
    const float* __restrict__ res, const float* __restrict__ wgt,
    const float* __restrict__ bia, float* __restrict__ x1,
    bf16* __restrict__ h2) {
  const int t = blockIdx.x, tid = threadIdx.x;
  const size_t base = (size_t)t * E;
  const int e0 = tid * 4;
  uint2 u0 = *(const uint2*)(P + base + e0);
  uint2 u1 = *(const uint2*)(P + (size_t)MT * E + base + e0);
  const bf16* p0 = (const bf16*)&u0;
  const bf16* p1 = (const bf16*)&u1;
  float4 b = *(const float4*)(bias + e0);
  float4 r = *(const float4*)(res + base + e0);
  float v4[4];
  v4[0] = (float)p0[0] + (float)p1[0] + b.x + r.x;
  v4[1] = (float)p0[1] + (float)p1[1] + b.y + r.y;
  v4[2] = (float)p0[2] + (float)p1[2] + b.z + r.z;
  v4[3] = (float)p0[3] + (float)p1[3] + b.w + r.w;
  *(float4*)(x1 + base + e0) = *(float4*)v4;

  float s = 0.f, ss = 0.f;
#pragma unroll
  for (int i = 0; i < 4; i++) { s += v4[i]; ss += v4[i] * v4[i]; }
  for (int off = 32; off > 0; off >>= 1) {
    s += __shfl_down(s, off, 64);
    ss += __shfl_down(ss, off, 64);
  }
  __shared__ float rs[4], rss[4], mv[2];
  const int w = tid >> 6;
  if ((tid & 63) == 0) { rs[w] = s; rss[w] = ss; }
  __syncthreads();
  if (tid == 0) {
    float S = rs[0] + rs[1] + rs[2] + rs[3];
    float SS = rss[0] + rss[1] + rss[2] + rss[3];
    float mean = S * (1.f / E);
    float var = SS * (1.f / E) - mean * mean;
    mv[0] = mean; mv[1] = rsqrtf(var + 1e-5f);
  }
  __syncthreads();
  const float mean = mv[0], rstd = mv[1];
  float4 wg = *(const float4*)(wgt + e0);
  float4 bb = *(const float4*)(bia + e0);
  bf16 o4[4];
  o4[0] = __float2bfloat16((v4[0] - mean) * rstd * wg.x + bb.x);
  o4[1] = __float2bfloat16((v4[1] - mean) * rstd * wg.y + bb.y);
  o4[2] = __float2bfloat16((v4[2] - mean) * rstd * wg.z + bb.z);
  o4[3] = __float2bfloat16((v4[3] - mean) * rstd * wg.w + bb.w);
  *(uint2*)(h2 + base + e0) = *(uint2*)o4;
}

// ---------------------------------------------------------------------------
// LayerNorm over E=1024 per token (f32 in, bf16 out). One block per token.
// ---------------------------------------------------------------------------
__global__ __launch_bounds__(256) void ln_kernel(
    const float* __restrict__ x, const float* __restrict__ wgt,
    const float* __restrict__ bia, bf16* __restrict__ out) {
  const int t = blockIdx.x, tid = threadIdx.x;
  const size_t base = (size_t)t * E;
  float v4[4], s = 0.f, ss = 0.f;
#pragma unroll
  for (int i = 0; i < 4; i++) {
    float v = x[base + i * 256 + tid];
    v4[i] = v; s += v; ss += v * v;
  }
  for (int off = 32; off > 0; off >>= 1) {
    s += __shfl_down(s, off, 64);
    ss += __shfl_down(ss, off, 64);
  }
  __shared__ float rs[4], rss[4], mv[2];
  const int w = tid >> 6;
  if ((tid & 63) == 0) { rs[w] = s; rss[w] = ss; }
  __syncthreads();
  if (tid == 0) {
    float S = rs[0] + rs[1] + rs[2] + rs[3];
    float SS = rss[0] + rss[1] + rss[2] + rss[3];
    float mean = S * (1.f / E);
    float var = SS * (1.f / E) - mean * mean;
    mv[0] = mean; mv[1] = rsqrtf(var + 1e-5f);
  }
  __syncthreads();
  const float mean = mv[0], rstd = mv[1];
#pragma unroll
  for (int i = 0; i < 4; i++) {
    const int e = i * 256 + tid;
    float r = (v4[i] - mean) * rstd * wgt[e] + bia[e];
    out[base + e] = __float2bfloat16(r);
  }
}

// ---------------------------------------------------------------------------
// Flash attention v9: 4 balanced blocks/CU + XCD locality. grid 1024 (1-D).
// Decode: x=bid&7, m=(bid>>3)&31, g=bid>>8, j=m>>2;
//   hh = (m&3)*8 + x   (head pinned to XCD x -> keeps 12 MB FETCH win)
//   qt = {j, 31-j, j+8, 23-j}[g]  (per-CU iters = 66, exactly balanced)
// One q-tile per block; v7 inner loop unchanged.
// ---------------------------------------------------------------------------
__global__ __launch_bounds__(256) void attn_kernel(
    const bf16* __restrict__ QK, const bf16* __restrict__ VT,
    bf16* __restrict__ O) {
  __shared__ __align__(16) bf16 KB[512 * 8];  // 8 KB
  __shared__ __align__(16) bf16 VB[512 * 8];  // 8 KB
  const int tid = threadIdx.x;
  const int w = tid >> 6, lane = tid & 63, quad = lane >> 4, l16 = lane & 15;
  const int bid = blockIdx.x;          // 0..1023
  const int x = bid & 7;
  const int m = (bid >> 3) & 31;
  const int g = bid >> 8;              // 0..3
  const int j = m >> 2;                // 0..7
  const int hh = (m & 3) * 8 + x;      // 0..31
  const int qt = (g == 0) ? j : (g == 1) ? (31 - j) : (g == 2) ? (j + 8) : (23 - j);
  const int n = hh >> 4, h = hh & 15;

  const bf16* Qp = QK + n * QKLD + h * Dd;
  const bf16* Kp = Qp + E;
  const bf16* Vp = VT + (size_t)hh * 64 * Lq;

  bf16* ldsK0 = KB + (size_t)(w * 64) * 8;
  bf16* ldsK1 = KB + (size_t)(256 + w * 64) * 8;
  bf16* ldsV0 = VB + (size_t)(w * 64) * 8;
  bf16* ldsV1 = VB + (size_t)(256 + w * 64) * 8;
  const int w8 = w * 8;

  const int ql = qt * 64 + w * 16 + l16;
  const bf16x8 aq0 = ld8(Qp + (size_t)ql * LDL + quad * 8);
  const bf16x8 aq1 = ld8(Qp + (size_t)ql * LDL + 32 + quad * 8);

  f32x4 o_acc[4];
#pragma unroll
  for (int d = 0; d < 4; d++)
#pragma unroll
    for (int r = 0; r < 4; r++) o_acc[d][r] = 0.f;
  float m_run = -3e30f, l_run = 0.f;

  for (int kt = 0; kt <= qt; ++kt) {
    const size_t kb = (size_t)kt * 64;

    async_lds16(Kp + (size_t)(kb + lane) * LDL + w8, ldsK0);
    async_lds16(Kp + (size_t)(kb + lane) * LDL + 32 + w8, ldsK1);
    async_lds16(Vp + (size_t)lane * Lq + kb + w8, ldsV0);
    async_lds16(Vp + (size_t)lane * Lq + kb + 32 + w8, ldsV1);
    __syncthreads();

    f32x4 s[4];
#pragma unroll
    for (int ks = 0; ks < 4; ks++) {
      const bf16x8 kc0 = ld8(&KB[(size_t)((quad)*64 + ks * 16 + l16) * 8]);
      const bf16x8 kc1 = ld8(&KB[(size_t)((4 + quad) * 64 + ks * 16 + l16) * 8]);
#pragma unroll
      for (int r = 0; r < 4; r++) s[ks][r] = 0.f;
      s[ks] = __builtin_amdgcn_mfma_f32_16x16x32_bf16(kc0, aq0, s[ks], 0, 0, 0);
      s[ks] = __builtin_amdgcn_mfma_f32_16x16x32_bf16(kc1, aq1, s[ks], 0, 0, 0);
    }

    if (kt == qt) {
#pragma unroll
      for (int ks = 0; ks < 4; ks++) {
#pragma unroll
        for (int r = 0; r < 4; r++) {
          const int kg = kt * 64 + ks * 16 + quad * 4 + r;
          if (kg > ql) s[ks][r] = -14427.0f;
        }
      }
    }

    float tmax = s[0][0];
#pragma unroll
    for (int ks = 0; ks < 4; ks++)
#pragma unroll
      for (int r = 0; r < 4; r++) tmax = fmaxf(tmax, s[ks][r]);
    tmax = fmaxf(tmax, __shfl_xor(tmax, 16, 64));
    tmax = fmaxf(tmax, __shfl_xor(tmax, 32, 64));
    const float mnew = fmaxf(m_run, tmax);
    const float alpha = exp2f(m_run - mnew);
    m_run = mnew;
    float rsum = 0.f;
    short4v pf[4];
#pragma unroll
    for (int ks = 0; ks < 4; ks++) {
#pragma unroll
      for (int r = 0; r < 4; r++) {
        const float pv = exp2f(s[ks][r] - mnew);
        rsum += pv;
        pf[ks][r] = bfbits(pv);
      }
    }
    rsum += __shfl_xor(rsum, 16, 64);
    rsum += __shfl_xor(rsum, 32, 64);
    l_run = l_run * alpha + rsum;
#pragma unroll
    for (int d = 0; d < 4; d++)
#pragma unroll
      for (int r = 0; r < 4; r++) o_acc[d][r] *= alpha;

#pragma unroll
    for (int d = 0; d < 4; d++) {
#pragma unroll
      for (int ks = 0; ks < 4; ks++) {
        const int gg = ks * 2 + (quad >> 1);
        const short4v av =
            *(const short4v*)&VB[(size_t)(gg * 64 + d * 16 + l16) * 8 + (quad & 1) * 4];
        o_acc[d] = __builtin_amdgcn_mfma_f32_16x16x16bf16_1k(av, pf[ks], o_acc[d], 0, 0, 0);
      }
    }
    __syncthreads();
  }

  const float inv_l = 1.f / fmaxf(l_run, 1e-30f);
  const size_t obase = (size_t)ql * (Nb * E) + (size_t)n * E + h * Dd;
#pragma unroll
  for (int d = 0; d < 4; d++)
#pragma unroll
    for (int r = 0; r < 4; r++)
      O[obase + d * 16 + quad * 4 + r] = __float2bfloat16(o_acc[d][r] * inv_l);
}

// ---------------------------------------------------------------------------
extern "C" void kernel_launch(void* const* d_in, const int* in_sizes, int n_in,
                              void* d_out, int out_size, void* d_ws, size_t ws_size,
                              hipStream_t stream) {
  const float* x    = (const float*)d_in[0];
  const float* ln1w = (const float*)d_in[1];
  const float* ln1b = (const float*)d_in[2];
  const float* wq   = (const float*)d_in[3];
  const float* bq   = (const float*)d_in[4];
  const float* wk   = (const float*)d_in[5];
  const float* bk   = (const float*)d_in[6];
  const float* wv   = (const float*)d_in[7];
  const float* bv   = (const float*)d_in[8];
  const float* wout = (const float*)d_in[9];
  const float* bout = (const float*)d_in[10];
  const float* ln2w = (const float*)d_in[11];
  const float* ln2b = (const float*)d_in[12];
  const float* fc1w = (const float*)d_in[13];
  const float* fc1b = (const float*)d_in[14];
  const float* fc2w = (const float*)d_in[15];
  const float* fc2b = (const float*)d_in[16];

  char* ws = (char*)d_ws;
  bf16* wqkvb = (bf16*)(ws);                        // 0-6 MB  [wq;wk;wv]
  bf16* woutb = (bf16*)(ws + ((size_t)6 << 20));    // 6-8 MB
  bf16* f1wb  = (bf16*)(ws + ((size_t)8 << 20));    // 8-16 MB
  bf16* f2wb  = (bf16*)(ws + ((size_t)16 << 20));   // 16-24 MB
  bf16* h1    = (bf16*)(ws + ((size_t)24 << 20));   // 24-32 MB (h2 reuses)
  bf16* qk    = (bf16*)(ws + ((size_t)32 << 20));   // 32-48 MB [4096][2048]
  bf16* vtg   = (bf16*)(ws + ((size_t)48 << 20));   // 48-56 MB V^T [32*64][2048]
  bf16* o     = (bf16*)(ws + ((size_t)56 << 20));   // 56-64 MB
  float* x1   = (float*)(ws + ((size_t)64 << 20));  // 64-80 MB f32
  bf16* Pout  = (bf16*)(ws + ((size_t)32 << 20));   // 32-48: out-proj splitK
  bf16* P01   = (bf16*)(ws);                        // 0-16: FC2 splitK partials
  bf16* f1    = (bf16*)(ws + ((size_t)32 << 20));   // 32-64 (qk,vtg,o dead)
  bf16* h2    = h1;
  float* outp = (float*)d_out;

  cvt_all_kernel<<<12288, 256, 0, stream>>>(wq, wk, wv, wout, fc1w, fc2w,
                                            wqkvb, woutb, f1wb, f2wb);

  ln_kernel<<<MT, 256, 0, stream>>>(x, ln1w, ln1b, h1);

  dim3 gQKV(3 * E / 128, MT / 128);   // (24,32)
  dim3 gE2(E / 128, MT / 128, 2);     // (8,32,2) split-K
  dim3 gF(Ff / 128, MT / 128);        // (32,32)

  // q pre-scale folded with log2(e) for exp2-domain softmax
  gemm_bt<4, 64><<<gQKV, 256, 0, stream>>>(h1, wqkvb, bq, bk, bv, E, E, 2048,
                                           0.125f * 1.44269504f, 1024, qk, vtg);

  attn_kernel<<<1024, 256, 0, stream>>>(qk, vtg, o);

  gemm_bt<3, 64><<<gE2, 256, 0, stream>>>(o, woutb, nullptr, nullptr, nullptr,
                                          E / 2, E, E, 1.f, 0, Pout, nullptr);
  redln_kernel<<<MT, 256, 0, stream>>>(Pout, bout, x, ln2w, ln2b, x1, h2);

  gemm_bt<2, 32><<<gF, 256, 0, stream>>>(h2, f1wb, fc1b, nullptr, nullptr,
                                         E, E, Ff, 1.f, 0, f1, nullptr);

  gemm_bt<3, 64><<<gE2, 256, 0, stream>>>(f1, f2wb, nullptr, nullptr, nullptr,
                                          Ff / 2, Ff, E, 1.f, 0, P01, nullptr);
  reduce2_kernel<<<MT * E / 1024, 256, 0, stream>>>(P01, fc2b, x1, outp);
}